// Round 9
// baseline (254.479 us; speedup 1.0000x reference)
//
#include <hip/hip_runtime.h>
#include <hip/hip_bf16.h>

#define TN 24
#define HID 64
#define LOG2E 1.4426950408889634f

// ws layout (bytes):
//   0     : gic [24*192 f32]  (scaled by log2e / 2log2e)   (18432)
//   18432 : bhn [64 f32]      (scaled by 2log2e)           (256)
//   18688 : wlc [96 f32]      (unscaled)                   (384)
//   19072 : frags [36][64] x 16B bf16x8 (scaled)           (36864)
#define WS_GIC_F   0
#define WS_BHN_F   4608
#define WS_WLC_F   4672
#define WS_FRAG_B  19072

// dynamic LDS layout (bytes), total 75392:
#define HHI_OFF   0        // ushort [4 pairs][32 elem][72]  18432
#define HLO_OFF   18432    // ushort [4 pairs][32 elem][72]  18432
#define WHH_OFF   36864    // 24 frags x 64 lanes x 16B      24576
#define WI_OFF    61440    // 12 frags x 64 lanes x 16B      12288
#define BHN_OFF   73728    // 64 f32
#define WLC_OFF   73984    // 96 f32
#define PARTS_OFF 74368    // [4][2][32] f32 = 1024
#define LDS_BYTES 75392

typedef __attribute__((ext_vector_type(8))) short bf16x8;
typedef __attribute__((ext_vector_type(4))) float f32x4;
typedef __attribute__((ext_vector_type(2))) float f32x2;

__device__ __forceinline__ ushort bf16rn(float f) {
    uint x = __float_as_uint(f);
    return (ushort)((x + 0x7fffu + ((x >> 16) & 1u)) >> 16);
}
__device__ __forceinline__ uint cvtpk_bf16(float lo, float hi) {
    uint r;
    asm("v_cvt_pk_bf16_f32 %0, %1, %2" : "=v"(r) : "v"(lo), "v"(hi));
    return r;
}
__device__ __forceinline__ float exp2p_(float x) {   // 2^x
    float r; asm("v_exp_f32 %0, %1" : "=v"(r) : "v"(x)); return r;
}
__device__ __forceinline__ float exp2n_(float x) {   // 2^-x (free neg modifier)
    float r; asm("v_exp_f32 %0, -%1" : "=v"(r) : "v"(x)); return r;
}
__device__ __forceinline__ float sigm(float v) {
    return __builtin_amdgcn_rcpf(1.0f + __expf(-v));
}

// ---------------- pre-kernel: build scaled gic + bf16 fragment tables in ws ----------------
extern "C" __global__ void __launch_bounds__(256)
traj_gru_pre(const float* __restrict__ Wloc, const float* __restrict__ bloc,
             const float* __restrict__ tt, const float* __restrict__ Wih,
             const float* __restrict__ Whh, const float* __restrict__ bih,
             const float* __restrict__ bhh, float* __restrict__ ws)
{
    const int b = blockIdx.x, tid = threadIdx.x;
    if (b < 36) {
        if (tid < 64) {
            const int er = tid & 15, cp = tid >> 4;
            const float* src;
            float s;
            if (b < 8) {            // wih R (0-3), Z (4-7): scale log2e
                int g = b >> 2, a = b & 3;
                src = Wih + (size_t)(g * 64 + a * 16 + er) * 64 + 8 * cp;
                s = LOG2E;
            } else if (b < 32) {    // whh frags: r,z -> log2e; n -> 2log2e
                int t = b - 8, g = t >> 3, r = t & 7, a = r >> 1, f = r & 1;
                src = Whh + (size_t)(g * 64 + a * 16 + er) * 64 + 32 * f + 8 * cp;
                s = (g == 2) ? 2.0f * LOG2E : LOG2E;
            } else {                // wih n-gate: 2log2e
                int a = b - 32;
                src = Wih + (size_t)(128 + a * 16 + er) * 64 + 8 * cp;
                s = 2.0f * LOG2E;
            }
            union { ushort u[8]; bf16x8 v; } fr;
            #pragma unroll
            for (int j = 0; j < 8; ++j) fr.u[j] = bf16rn(s * src[j]);
            *(bf16x8*)((char*)ws + WS_FRAG_B + ((size_t)b * 64 + tid) * 16) = fr.v;
        }
    } else if (b < 38) {
        const int base = (b - 36) * 2304;
        for (int i = tid; i < 2304; i += 256) {
            int idx = base + i, t = idx / 192, g = idx % 192;
            float acc = bih[g] + (g < 128 ? bhh[g] : 0.0f);
            const float* ttr = tt + t * 32;
            const float* wr  = Wih + g * 64 + 32;
            #pragma unroll
            for (int k = 0; k < 32; ++k) {
                float e = ttr[k];
                e = fmaxf(e, 0.2f * e);
                acc = fmaf(wr[k], e, acc);
            }
            ws[WS_GIC_F + idx] = acc * (g < 128 ? LOG2E : 2.0f * LOG2E);
        }
    } else {
        if (tid < 64) ws[WS_BHN_F + tid] = 2.0f * LOG2E * bhh[128 + tid];
        if (tid < 96) ws[WS_WLC_F + tid] = (tid < 64) ? Wloc[tid] : bloc[tid - 64];
    }
}

// ---------- main kernel: wave pair shares 32 elements; each wave owns 32 hidden dims ----------
extern "C" __global__ void __launch_bounds__(512, 4)
traj_gru_mfma(const float* __restrict__ x, const float* __restrict__ ws,
              const float* __restrict__ Wpred, const float* __restrict__ bpred,
              float* __restrict__ out)
{
    extern __shared__ __align__(16) char L[];
    float*  Lf   = (float*)L;
    char*   whhS = L + WHH_OFF;
    char*   wiS  = L + WI_OFF;

    const int tid  = threadIdx.x;
    const int lane = tid & 63;
    const int wid  = tid >> 6;       // wave 0..7
    const int pair = wid >> 1;       // element group 0..3
    const int half = wid & 1;        // output half: rows [32*half, 32*half+32)
    const int er   = lane & 15;
    const int cp   = lane >> 4;

    // ---- stage all 36 weight frags ws -> LDS (coalesced 16B chunks) ----
    const char* fb = (const char*)ws + WS_FRAG_B;
    for (int i = tid; i < 36 * 64; i += 512) {
        int f = i >> 6, l = i & 63;
        bf16x8 v = *(const bf16x8*)(fb + (size_t)i * 16);
        char* dst;
        if (f < 8)       dst = wiS  + ((size_t)f * 64 + l) * 16;
        else if (f < 32) dst = whhS + ((size_t)(f - 8) * 64 + l) * 16;
        else             dst = wiS  + ((size_t)(f - 24) * 64 + l) * 16;
        *(bf16x8*)dst = v;
    }
    if (tid < 64) Lf[BHN_OFF / 4 + tid] = ws[WS_BHN_F + tid];
    if (tid < 96) Lf[WLC_OFF / 4 + tid] = ws[WS_WLC_F + tid];
    __syncthreads();

    const f32x2* wlc2 = (const f32x2*)(Lf + WLC_OFF / 4);
    ushort* Hhi = (ushort*)(L + HHI_OFF) + (size_t)(pair * 32) * 72;
    ushort* Hlo = (ushort*)(L + HLO_OFF) + (size_t)(pair * 32) * 72;

    // bhn accumulator-init for this half's rows (loop-invariant)
    f32x4 bhnR[2];
    #pragma unroll
    for (int a = 0; a < 2; ++a)
        bhnR[a] = *(const f32x4*)(Lf + BHN_OFF / 4 + (half * 2 + a) * 16 + 4 * cp);

    const int ego = (blockIdx.x * 4 + pair) * 32;
    const float* xr0 = x + (size_t)(ego + er) * (TN * 2);
    const float* xr1 = x + (size_t)(ego + 16 + er) * (TN * 2);

    f32x2 hold2[2][2][2];   // [bf][a][p]
    #pragma unroll
    for (int bf = 0; bf < 2; ++bf)
        #pragma unroll
        for (int a = 0; a < 2; ++a)
            #pragma unroll
            for (int p = 0; p < 2; ++p) hold2[bf][a][p] = (f32x2){0.0f, 0.0f};

    const f32x2 one2    = {1.0f, 1.0f};
    const f32x2 negtwo2 = {-2.0f, -2.0f};

    float2 xv0 = *(const float2*)(xr0);
    float2 xv1 = *(const float2*)(xr1);

    #pragma unroll 1
    for (int t = 0; t < TN; ++t) {
        const int tn = (t + 1 < TN) ? t + 1 : TN - 1;
        float2 xv0n = *(const float2*)(xr0 + tn * 2);
        float2 xv1n = *(const float2*)(xr1 + tn * 2);

        // ex B-frags (computed redundantly by both waves of the pair; cheap)
        union { uint u[4]; bf16x8 v; } exf0, exf1;
        {
            f32x2 xx0 = {xv0.x, xv0.x}, yy0 = {xv0.y, xv0.y};
            f32x2 xx1 = {xv1.x, xv1.x}, yy1 = {xv1.y, xv1.y};
            #pragma unroll
            for (int jp = 0; jp < 4; ++jp) {
                int kp = 4 * cp + jp;
                f32x2 w1 = wlc2[kp], w2 = wlc2[16 + kp], bl = wlc2[32 + kp];
                f32x2 v0 = __builtin_elementwise_fma(xx0, w1,
                           __builtin_elementwise_fma(yy0, w2, bl));
                f32x2 v1 = __builtin_elementwise_fma(xx1, w1,
                           __builtin_elementwise_fma(yy1, w2, bl));
                exf0.u[jp] = cvtpk_bf16(fmaxf(v0.x, 0.2f * v0.x), fmaxf(v0.y, 0.2f * v0.y));
                exf1.u[jp] = cvtpk_bf16(fmaxf(v1.x, 0.2f * v1.x), fmaxf(v1.y, 0.2f * v1.y));
            }
        }

        // gic init for this half's rows (global loads, L1/L2-resident)
        const float* gt = ws + WS_GIC_F + t * 192;
        f32x4 gR[2], gZ[2], gNi[2];
        #pragma unroll
        for (int a = 0; a < 2; ++a) {
            const int ao = half * 2 + a;
            gR[a]  = *(const f32x4*)(gt + ao * 16 + 4 * cp);
            gZ[a]  = *(const f32x4*)(gt + 64 + ao * 16 + 4 * cp);
            gNi[a] = *(const f32x4*)(gt + 128 + ao * 16 + 4 * cp);
        }

        f32x4 accR[2][2], accZ[2][2], accNi[2][2], accNh[2][2];

        // input-part MFMAs (K=32)
        #pragma unroll
        for (int a = 0; a < 2; ++a) {
            const int ao = half * 2 + a;
            bf16x8 wr = *(const bf16x8*)(wiS + ((size_t)ao * 64 + lane) * 16);
            bf16x8 wz = *(const bf16x8*)(wiS + ((size_t)(4 + ao) * 64 + lane) * 16);
            bf16x8 wn = *(const bf16x8*)(wiS + ((size_t)(8 + ao) * 64 + lane) * 16);
            accR[0][a]  = __builtin_amdgcn_mfma_f32_16x16x32_bf16(wr, exf0.v, gR[a], 0, 0, 0);
            accR[1][a]  = __builtin_amdgcn_mfma_f32_16x16x32_bf16(wr, exf1.v, gR[a], 0, 0, 0);
            accZ[0][a]  = __builtin_amdgcn_mfma_f32_16x16x32_bf16(wz, exf0.v, gZ[a], 0, 0, 0);
            accZ[1][a]  = __builtin_amdgcn_mfma_f32_16x16x32_bf16(wz, exf1.v, gZ[a], 0, 0, 0);
            accNi[0][a] = __builtin_amdgcn_mfma_f32_16x16x32_bf16(wn, exf0.v, gNi[a], 0, 0, 0);
            accNi[1][a] = __builtin_amdgcn_mfma_f32_16x16x32_bf16(wn, exf1.v, gNi[a], 0, 0, 0);
        }

        // recurrent MFMAs (full-K h read; r,z hi-only; n hi+lo)
        if (t > 0) {
            #pragma unroll
            for (int bf = 0; bf < 2; ++bf) {
                const int row = (bf * 16 + er) * 72;
                bf16x8 hh0 = *(const bf16x8*)&Hhi[row + 8 * cp];
                bf16x8 hh1 = *(const bf16x8*)&Hhi[row + 32 + 8 * cp];
                bf16x8 hl0 = *(const bf16x8*)&Hlo[row + 8 * cp];
                bf16x8 hl1 = *(const bf16x8*)&Hlo[row + 32 + 8 * cp];
                #pragma unroll
                for (int a = 0; a < 2; ++a) {
                    const int ao = half * 2 + a;
                    bf16x8 wr0 = *(const bf16x8*)(whhS + ((size_t)(ao * 2 + 0) * 64 + lane) * 16);
                    bf16x8 wr1 = *(const bf16x8*)(whhS + ((size_t)(ao * 2 + 1) * 64 + lane) * 16);
                    accR[bf][a] = __builtin_amdgcn_mfma_f32_16x16x32_bf16(wr0, hh0, accR[bf][a], 0, 0, 0);
                    accR[bf][a] = __builtin_amdgcn_mfma_f32_16x16x32_bf16(wr1, hh1, accR[bf][a], 0, 0, 0);
                    bf16x8 wz0 = *(const bf16x8*)(whhS + ((size_t)(8 + ao * 2 + 0) * 64 + lane) * 16);
                    bf16x8 wz1 = *(const bf16x8*)(whhS + ((size_t)(8 + ao * 2 + 1) * 64 + lane) * 16);
                    accZ[bf][a] = __builtin_amdgcn_mfma_f32_16x16x32_bf16(wz0, hh0, accZ[bf][a], 0, 0, 0);
                    accZ[bf][a] = __builtin_amdgcn_mfma_f32_16x16x32_bf16(wz1, hh1, accZ[bf][a], 0, 0, 0);
                    bf16x8 wn0 = *(const bf16x8*)(whhS + ((size_t)(16 + ao * 2 + 0) * 64 + lane) * 16);
                    bf16x8 wn1 = *(const bf16x8*)(whhS + ((size_t)(16 + ao * 2 + 1) * 64 + lane) * 16);
                    accNh[bf][a] = __builtin_amdgcn_mfma_f32_16x16x32_bf16(wn0, hh0, bhnR[a], 0, 0, 0);
                    accNh[bf][a] = __builtin_amdgcn_mfma_f32_16x16x32_bf16(wn1, hh1, accNh[bf][a], 0, 0, 0);
                    accNh[bf][a] = __builtin_amdgcn_mfma_f32_16x16x32_bf16(wn0, hl0, accNh[bf][a], 0, 0, 0);
                    accNh[bf][a] = __builtin_amdgcn_mfma_f32_16x16x32_bf16(wn1, hl1, accNh[bf][a], 0, 0, 0);
                }
            }
        } else {
            #pragma unroll
            for (int bf = 0; bf < 2; ++bf)
                #pragma unroll
                for (int a = 0; a < 2; ++a) accNh[bf][a] = bhnR[a];
        }

        __syncthreads();   // barrier B: all h reads done before any h writes

        // epilogue: this half's 32 rows; packed-f32 gate math
        #pragma unroll
        for (int bf = 0; bf < 2; ++bf) {
            const int row = (bf * 16 + er) * 72;
            #pragma unroll
            for (int a = 0; a < 2; ++a) {
                const int ao = half * 2 + a;
                uint hiw[2], low[2];
                #pragma unroll
                for (int p = 0; p < 2; ++p) {
                    f32x2 aR  = {accR[bf][a][2 * p],  accR[bf][a][2 * p + 1]};
                    f32x2 aZ  = {accZ[bf][a][2 * p],  accZ[bf][a][2 * p + 1]};
                    f32x2 aNi = {accNi[bf][a][2 * p], accNi[bf][a][2 * p + 1]};
                    f32x2 aNh = {accNh[bf][a][2 * p], accNh[bf][a][2 * p + 1]};
                    f32x2 eR = {exp2n_(aR.x), exp2n_(aR.y)};
                    f32x2 eZ = {exp2n_(aZ.x), exp2n_(aZ.y)};
                    f32x2 dR = eR + one2;
                    f32x2 dZ = eZ + one2;
                    f32x2 r  = {__builtin_amdgcn_rcpf(dR.x), __builtin_amdgcn_rcpf(dR.y)};
                    f32x2 z  = {__builtin_amdgcn_rcpf(dZ.x), __builtin_amdgcn_rcpf(dZ.y)};
                    f32x2 np = __builtin_elementwise_fma(r, aNh, aNi);
                    f32x2 e2 = {exp2p_(np.x), exp2p_(np.y)};
                    f32x2 d2 = e2 + one2;
                    f32x2 rc = {__builtin_amdgcn_rcpf(d2.x), __builtin_amdgcn_rcpf(d2.y)};
                    f32x2 n  = __builtin_elementwise_fma(rc, negtwo2, one2);
                    f32x2 hm = hold2[bf][a][p] - n;
                    f32x2 h  = __builtin_elementwise_fma(z, hm, n);
                    hold2[bf][a][p] = h;
                    uint whi = cvtpk_bf16(h.x, h.y);
                    f32x2 hh = {__uint_as_float(whi << 16), __uint_as_float(whi & 0xffff0000u)};
                    f32x2 lo = h - hh;
                    hiw[p] = whi;
                    low[p] = cvtpk_bf16(lo.x, lo.y);
                }
                uint2 whiv = {hiw[0], hiw[1]};
                uint2 wlov = {low[0], low[1]};
                *(uint2*)&Hhi[row + 16 * ao + 4 * cp] = whiv;
                *(uint2*)&Hlo[row + 16 * ao + 4 * cp] = wlov;
            }
        }

        __syncthreads();   // barrier A: h writes visible before next step's reads

        xv0 = xv0n;
        xv1 = xv1n;
    }

    // ---- prediction head: per-wave partials over its 32 dims, pair-sum via LDS ----
    float p0 = 0.0f, p1 = 0.0f;
    #pragma unroll
    for (int a = 0; a < 2; ++a) {
        const int ao = half * 2 + a;
        f32x4 wp = *(const f32x4*)(Wpred + 16 * ao + 4 * cp);
        #pragma unroll
        for (int p = 0; p < 2; ++p) {
            p0 = fmaf(hold2[0][a][p].x, wp[2 * p], p0);
            p0 = fmaf(hold2[0][a][p].y, wp[2 * p + 1], p0);
            p1 = fmaf(hold2[1][a][p].x, wp[2 * p], p1);
            p1 = fmaf(hold2[1][a][p].y, wp[2 * p + 1], p1);
        }
    }
    p0 += __shfl_xor(p0, 16);  p0 += __shfl_xor(p0, 32);
    p1 += __shfl_xor(p1, 16);  p1 += __shfl_xor(p1, 32);

    float* parts = Lf + PARTS_OFF / 4;
    if (cp == 0) {
        parts[(pair * 2 + half) * 32 + er]      = p0;
        parts[(pair * 2 + half) * 32 + 16 + er] = p1;
    }
    __syncthreads();
    if (half == 0 && cp == 0) {
        float bp = bpred[0];
        float q0 = parts[(pair * 2 + 1) * 32 + er];
        float q1 = parts[(pair * 2 + 1) * 32 + 16 + er];
        out[ego + er]      = sigm(p0 + q0 + bp);
        out[ego + 16 + er] = sigm(p1 + q1 + bp);
    }
}

extern "C" void kernel_launch(void* const* d_in, const int* in_sizes, int n_in,
                              void* d_out, int out_size, void* d_ws, size_t ws_size,
                              hipStream_t stream) {
    const float* x     = (const float*)d_in[0];
    const float* Wloc  = (const float*)d_in[1];
    const float* bloc  = (const float*)d_in[2];
    const float* tt    = (const float*)d_in[3];
    const float* Wih   = (const float*)d_in[4];
    const float* Whh   = (const float*)d_in[5];
    const float* bih   = (const float*)d_in[6];
    const float* bhh   = (const float*)d_in[7];
    const float* Wpred = (const float*)d_in[8];
    const float* bpred = (const float*)d_in[9];
    float* out = (float*)d_out;
    float* ws  = (float*)d_ws;

    (void)hipFuncSetAttribute((const void*)traj_gru_mfma,
                              hipFuncAttributeMaxDynamicSharedMemorySize, LDS_BYTES);

    hipLaunchKernelGGL(traj_gru_pre, dim3(39), dim3(256), 0, stream,
                       Wloc, bloc, tt, Wih, Whh, bih, bhh, ws);
    // 65536 elements / (4 pairs * 32 elem) = 512 blocks of 512 threads = 2 blocks/CU
    hipLaunchKernelGGL(traj_gru_mfma, dim3(512), dim3(512), LDS_BYTES, stream,
                       x, ws, Wpred, bpred, out);
}

// Round 10
// 120.409 us; speedup vs baseline: 2.1134x; 2.1134x over previous
//
#include <hip/hip_runtime.h>
#include <hip/hip_bf16.h>

#define TN 24
#define HID 64
#define LOG2E 1.4426950408889634f

// ws layout (bytes):
//   0     : gic [24*192 f32]  (scaled by log2e / 2log2e)   (18432)
//   18432 : bhn [64 f32]      (scaled by 2log2e)           (256)
//   18688 : wlc [96 f32]      (unscaled)                   (384)
//   19072 : frags [36][64] x 16B bf16x8 (scaled)           (36864)
#define WS_GIC_F   0
#define WS_BHN_F   4608
#define WS_WLC_F   4672
#define WS_FRAG_B  19072

// dynamic LDS layout (bytes), total 74368 (2 blocks/CU):
#define HHI_OFF  0        // ushort [8][16][72]  18432
#define HLO_OFF  18432    // ushort [8][16][72]  18432
#define WHH_OFF  36864    // 24 frags x 64 lanes x 16B  24576
#define WI_OFF   61440    // 12 frags x 64 lanes x 16B  12288
#define BHN_OFF  73728    // 64 f32 (unused by main loop now)
#define WLC_OFF  73984    // 96 f32
#define LDS_BYTES 74368

typedef __attribute__((ext_vector_type(8))) short bf16x8;
typedef __attribute__((ext_vector_type(4))) float f32x4;
typedef __attribute__((ext_vector_type(2))) float f32x2;

__device__ __forceinline__ ushort bf16rn(float f) {
    uint x = __float_as_uint(f);
    return (ushort)((x + 0x7fffu + ((x >> 16) & 1u)) >> 16);
}
__device__ __forceinline__ uint cvtpk_bf16(float lo, float hi) {
    uint r;
    asm("v_cvt_pk_bf16_f32 %0, %1, %2" : "=v"(r) : "v"(lo), "v"(hi));
    return r;
}
__device__ __forceinline__ float exp2p_(float x) {   // 2^x
    float r; asm("v_exp_f32 %0, %1" : "=v"(r) : "v"(x)); return r;
}
__device__ __forceinline__ float exp2n_(float x) {   // 2^-x (free neg modifier)
    float r; asm("v_exp_f32 %0, -%1" : "=v"(r) : "v"(x)); return r;
}
__device__ __forceinline__ float sigm(float v) {
    return __builtin_amdgcn_rcpf(1.0f + __expf(-v));
}

// ---------------- pre-kernel: build scaled gic + bf16 fragment tables in ws ----------------
extern "C" __global__ void __launch_bounds__(256)
traj_gru_pre(const float* __restrict__ Wloc, const float* __restrict__ bloc,
             const float* __restrict__ tt, const float* __restrict__ Wih,
             const float* __restrict__ Whh, const float* __restrict__ bih,
             const float* __restrict__ bhh, float* __restrict__ ws)
{
    const int b = blockIdx.x, tid = threadIdx.x;
    if (b < 36) {
        if (tid < 64) {
            const int er = tid & 15, cp = tid >> 4;
            const float* src;
            float s;
            if (b < 8) {            // wih R (0-3), Z (4-7): scale log2e
                int g = b >> 2, a = b & 3;
                src = Wih + (size_t)(g * 64 + a * 16 + er) * 64 + 8 * cp;
                s = LOG2E;
            } else if (b < 32) {    // whh frags: r,z -> log2e; n -> 2log2e
                int t = b - 8, g = t >> 3, r = t & 7, a = r >> 1, f = r & 1;
                src = Whh + (size_t)(g * 64 + a * 16 + er) * 64 + 32 * f + 8 * cp;
                s = (g == 2) ? 2.0f * LOG2E : LOG2E;
            } else {                // wih n-gate: 2log2e
                int a = b - 32;
                src = Wih + (size_t)(128 + a * 16 + er) * 64 + 8 * cp;
                s = 2.0f * LOG2E;
            }
            union { ushort u[8]; bf16x8 v; } fr;
            #pragma unroll
            for (int j = 0; j < 8; ++j) fr.u[j] = bf16rn(s * src[j]);
            *(bf16x8*)((char*)ws + WS_FRAG_B + ((size_t)b * 64 + tid) * 16) = fr.v;
        }
    } else if (b < 38) {
        const int base = (b - 36) * 2304;
        for (int i = tid; i < 2304; i += 256) {
            int idx = base + i, t = idx / 192, g = idx % 192;
            float acc = bih[g] + (g < 128 ? bhh[g] : 0.0f);
            const float* ttr = tt + t * 32;
            const float* wr  = Wih + g * 64 + 32;
            #pragma unroll
            for (int k = 0; k < 32; ++k) {
                float e = ttr[k];
                e = fmaxf(e, 0.2f * e);
                acc = fmaf(wr[k], e, acc);
            }
            ws[WS_GIC_F + idx] = acc * (g < 128 ? LOG2E : 2.0f * LOG2E);
        }
    } else {
        if (tid < 64) ws[WS_BHN_F + tid] = 2.0f * LOG2E * bhh[128 + tid];
        if (tid < 96) ws[WS_WLC_F + tid] = (tid < 64) ? Wloc[tid] : bloc[tid - 64];
    }
}

// ---------------- main kernel (R7 structure, (512,2) register regime) ----------------
extern "C" __global__ void __launch_bounds__(512, 2)
traj_gru_mfma(const float* __restrict__ x, const float* __restrict__ ws,
              const float* __restrict__ Wpred, const float* __restrict__ bpred,
              float* __restrict__ out)
{
    extern __shared__ __align__(16) char L[];
    float*  Lf   = (float*)L;
    char*   whhS = L + WHH_OFF;
    char*   wiS  = L + WI_OFF;

    const int tid  = threadIdx.x;
    const int lane = tid & 63;
    const int wid  = tid >> 6;       // wave 0..7
    const int er   = lane & 15;      // A-row / B-col / D-col index
    const int cp   = lane >> 4;      // k-block / D-row-block

    // ---- stage all 36 weight frags ws -> LDS (coalesced 16B chunks) ----
    const char* fb = (const char*)ws + WS_FRAG_B;
    for (int i = tid; i < 36 * 64; i += 512) {
        int f = i >> 6, l = i & 63;
        bf16x8 v = *(const bf16x8*)(fb + (size_t)i * 16);
        char* dst;
        if (f < 8)       dst = wiS  + ((size_t)f * 64 + l) * 16;        // R,Z input frags
        else if (f < 32) dst = whhS + ((size_t)(f - 8) * 64 + l) * 16;  // recurrent frags
        else             dst = wiS  + ((size_t)(f - 24) * 64 + l) * 16; // n input frags -> 8..11
        *(bf16x8*)dst = v;
    }
    if (tid < 96) Lf[WLC_OFF / 4 + tid] = ws[WS_WLC_F + tid];
    __syncthreads();   // the only barrier

    const f32x2* wlc2 = (const f32x2*)(Lf + WLC_OFF / 4);
    ushort* Hhi = (ushort*)(L + HHI_OFF) + (size_t)(wid * 16) * 72;
    ushort* Hlo = (ushort*)(L + HLO_OFF) + (size_t)(wid * 16) * 72;

    // bhn accumulator-init: loop-invariant -> registers (from global ws, no sync needed)
    f32x4 bhnR[4];
    #pragma unroll
    for (int a = 0; a < 4; ++a)
        bhnR[a] = *(const f32x4*)(ws + WS_BHN_F + a * 16 + 4 * cp);

    // ---- main loop: wave owns 16 elements ----
    const long long eg = (long long)(blockIdx.x * 8 + wid) * 16 + er;
    const float* xr = x + eg * (TN * 2);

    f32x2 hold2[4][2];
    #pragma unroll
    for (int a = 0; a < 4; ++a)
        #pragma unroll
        for (int p = 0; p < 2; ++p) hold2[a][p] = (f32x2){0.0f, 0.0f};

    const f32x2 one2    = {1.0f, 1.0f};
    const f32x2 negtwo2 = {-2.0f, -2.0f};

    float2 xv = *(const float2*)(xr);   // t=0 prefetched

    #pragma unroll 1
    for (int t = 0; t < TN; ++t) {
        const int tn = (t + 1 < TN) ? t + 1 : TN - 1;
        float2 xv_next = *(const float2*)(xr + tn * 2);

        // ex B-frag: ex[k = 8cp+j][elem = er]
        union { uint u[4]; bf16x8 v; } exf;
        {
            f32x2 xx = {xv.x, xv.x}, yy = {xv.y, xv.y};
            #pragma unroll
            for (int jp = 0; jp < 4; ++jp) {
                int kp = 4 * cp + jp;
                f32x2 w1 = wlc2[kp], w2 = wlc2[16 + kp], bl = wlc2[32 + kp];
                f32x2 v = __builtin_elementwise_fma(xx, w1,
                          __builtin_elementwise_fma(yy, w2, bl));
                float v0 = fmaxf(v.x, 0.2f * v.x);
                float v1 = fmaxf(v.y, 0.2f * v.y);
                exf.u[jp] = cvtpk_bf16(v0, v1);
            }
        }

        // accumulator init: gic from global (L1/L2-resident), bhn from registers
        const float* gt = ws + WS_GIC_F + t * 192;
        f32x4 accR[4], accZ[4], accNi[4], accNh[4];
        #pragma unroll
        for (int a = 0; a < 4; ++a) {
            accR[a]  = *(const f32x4*)(gt + a * 16 + 4 * cp);
            accZ[a]  = *(const f32x4*)(gt + 64 + a * 16 + 4 * cp);
            accNi[a] = *(const f32x4*)(gt + 128 + a * 16 + 4 * cp);
            accNh[a] = bhnR[a];
        }

        // input-part MFMAs (K=32), weights from LDS
        #pragma unroll
        for (int a = 0; a < 4; ++a) {
            bf16x8 wr = *(const bf16x8*)(wiS + ((size_t)a * 64 + lane) * 16);
            bf16x8 wz = *(const bf16x8*)(wiS + ((size_t)(4 + a) * 64 + lane) * 16);
            bf16x8 wn = *(const bf16x8*)(wiS + ((size_t)(8 + a) * 64 + lane) * 16);
            accR[a]  = __builtin_amdgcn_mfma_f32_16x16x32_bf16(wr, exf.v, accR[a], 0, 0, 0);
            accZ[a]  = __builtin_amdgcn_mfma_f32_16x16x32_bf16(wz, exf.v, accZ[a], 0, 0, 0);
            accNi[a] = __builtin_amdgcn_mfma_f32_16x16x32_bf16(wn, exf.v, accNi[a], 0, 0, 0);
        }

        // recurrent MFMAs (K=64, h = hi + lo split bf16; r,z hi-only), weights from LDS
        if (t > 0) {
            bf16x8 hhi0 = *(const bf16x8*)&Hhi[er * 72 + 8 * cp];
            bf16x8 hhi1 = *(const bf16x8*)&Hhi[er * 72 + 32 + 8 * cp];
            bf16x8 hlo0 = *(const bf16x8*)&Hlo[er * 72 + 8 * cp];
            bf16x8 hlo1 = *(const bf16x8*)&Hlo[er * 72 + 32 + 8 * cp];
            #pragma unroll
            for (int a = 0; a < 4; ++a) {
                bf16x8 wr0 = *(const bf16x8*)(whhS + ((size_t)(a * 2 + 0) * 64 + lane) * 16);
                bf16x8 wr1 = *(const bf16x8*)(whhS + ((size_t)(a * 2 + 1) * 64 + lane) * 16);
                accR[a] = __builtin_amdgcn_mfma_f32_16x16x32_bf16(wr0, hhi0, accR[a], 0, 0, 0);
                accR[a] = __builtin_amdgcn_mfma_f32_16x16x32_bf16(wr1, hhi1, accR[a], 0, 0, 0);
                bf16x8 wz0 = *(const bf16x8*)(whhS + ((size_t)(8 + a * 2 + 0) * 64 + lane) * 16);
                bf16x8 wz1 = *(const bf16x8*)(whhS + ((size_t)(8 + a * 2 + 1) * 64 + lane) * 16);
                accZ[a] = __builtin_amdgcn_mfma_f32_16x16x32_bf16(wz0, hhi0, accZ[a], 0, 0, 0);
                accZ[a] = __builtin_amdgcn_mfma_f32_16x16x32_bf16(wz1, hhi1, accZ[a], 0, 0, 0);
                bf16x8 wn0 = *(const bf16x8*)(whhS + ((size_t)(16 + a * 2 + 0) * 64 + lane) * 16);
                bf16x8 wn1 = *(const bf16x8*)(whhS + ((size_t)(16 + a * 2 + 1) * 64 + lane) * 16);
                accNh[a] = __builtin_amdgcn_mfma_f32_16x16x32_bf16(wn0, hhi0, accNh[a], 0, 0, 0);
                accNh[a] = __builtin_amdgcn_mfma_f32_16x16x32_bf16(wn1, hhi1, accNh[a], 0, 0, 0);
                accNh[a] = __builtin_amdgcn_mfma_f32_16x16x32_bf16(wn0, hlo0, accNh[a], 0, 0, 0);
                accNh[a] = __builtin_amdgcn_mfma_f32_16x16x32_bf16(wn1, hlo1, accNh[a], 0, 0, 0);
            }
        }

        // epilogue: packed-f32 gate math; acc pre-scaled by log2e (r,z) / 2log2e (n)
        #pragma unroll
        for (int a = 0; a < 4; ++a) {
            uint hiw[2], low[2];
            #pragma unroll
            for (int p = 0; p < 2; ++p) {
                f32x2 aR  = {accR[a][2 * p],  accR[a][2 * p + 1]};
                f32x2 aZ  = {accZ[a][2 * p],  accZ[a][2 * p + 1]};
                f32x2 aNi = {accNi[a][2 * p], accNi[a][2 * p + 1]};
                f32x2 aNh = {accNh[a][2 * p], accNh[a][2 * p + 1]};
                f32x2 eR = {exp2n_(aR.x), exp2n_(aR.y)};
                f32x2 eZ = {exp2n_(aZ.x), exp2n_(aZ.y)};
                f32x2 dR = eR + one2;
                f32x2 dZ = eZ + one2;
                f32x2 r  = {__builtin_amdgcn_rcpf(dR.x), __builtin_amdgcn_rcpf(dR.y)};
                f32x2 z  = {__builtin_amdgcn_rcpf(dZ.x), __builtin_amdgcn_rcpf(dZ.y)};
                f32x2 np = __builtin_elementwise_fma(r, aNh, aNi);     // 2log2e * npre
                f32x2 e2 = {exp2p_(np.x), exp2p_(np.y)};
                f32x2 d2 = e2 + one2;
                f32x2 rc = {__builtin_amdgcn_rcpf(d2.x), __builtin_amdgcn_rcpf(d2.y)};
                f32x2 n  = __builtin_elementwise_fma(rc, negtwo2, one2);  // tanh
                f32x2 hm = hold2[a][p] - n;
                f32x2 h  = __builtin_elementwise_fma(z, hm, n);
                hold2[a][p] = h;
                uint whi = cvtpk_bf16(h.x, h.y);
                f32x2 hh = {__uint_as_float(whi << 16), __uint_as_float(whi & 0xffff0000u)};
                f32x2 lo = h - hh;
                hiw[p] = whi;
                low[p] = cvtpk_bf16(lo.x, lo.y);
            }
            uint2 whiv = {hiw[0], hiw[1]};
            uint2 wlov = {low[0], low[1]};
            *(uint2*)&Hhi[er * 72 + 16 * a + 4 * cp] = whiv;
            *(uint2*)&Hlo[er * 72 + 16 * a + 4 * cp] = wlov;
        }

        xv = xv_next;
    }

    // ---- prediction head ----
    float part = 0.0f;
    #pragma unroll
    for (int a = 0; a < 4; ++a) {
        f32x4 wp = *(const f32x4*)(Wpred + 16 * a + 4 * cp);
        #pragma unroll
        for (int p = 0; p < 2; ++p) {
            part = fmaf(hold2[a][p].x, wp[2 * p], part);
            part = fmaf(hold2[a][p].y, wp[2 * p + 1], part);
        }
    }
    part += __shfl_xor(part, 16);
    part += __shfl_xor(part, 32);
    if (cp == 0) out[eg] = sigm(part + bpred[0]);
}

extern "C" void kernel_launch(void* const* d_in, const int* in_sizes, int n_in,
                              void* d_out, int out_size, void* d_ws, size_t ws_size,
                              hipStream_t stream) {
    const float* x     = (const float*)d_in[0];
    const float* Wloc  = (const float*)d_in[1];
    const float* bloc  = (const float*)d_in[2];
    const float* tt    = (const float*)d_in[3];
    const float* Wih   = (const float*)d_in[4];
    const float* Whh   = (const float*)d_in[5];
    const float* bih   = (const float*)d_in[6];
    const float* bhh   = (const float*)d_in[7];
    const float* Wpred = (const float*)d_in[8];
    const float* bpred = (const float*)d_in[9];
    float* out = (float*)d_out;
    float* ws  = (float*)d_ws;

    (void)hipFuncSetAttribute((const void*)traj_gru_mfma,
                              hipFuncAttributeMaxDynamicSharedMemorySize, LDS_BYTES);

    hipLaunchKernelGGL(traj_gru_pre, dim3(39), dim3(256), 0, stream,
                       Wloc, bloc, tt, Wih, Whh, bih, bhh, ws);
    // 65536 elements / (8 waves * 16 elem) = 512 blocks of 512 threads = 2 blocks/CU
    hipLaunchKernelGGL(traj_gru_mfma, dim3(512), dim3(512), LDS_BYTES, stream,
                       x, ws, Wpred, bpred, out);
}

// Round 11
// 106.423 us; speedup vs baseline: 2.3912x; 1.1314x over previous
//
#include <hip/hip_runtime.h>
#include <hip/hip_bf16.h>

#define TN 24
#define HID 64
#define LOG2E 1.4426950408889634f

// ws layout (bytes):
//   0     : gic [24*192 f32]  (scaled by log2e / 2log2e)   (18432)
//   18432 : bhn [64 f32]      (scaled by 2log2e)           (256)
//   18688 : wlc [96 f32]      (unscaled)                   (384)
//   19072 : frags [36][64] x 16B bf16x8 (scaled)           (36864)
#define WS_GIC_F   0
#define WS_BHN_F   4608
#define WS_WLC_F   4672
#define WS_FRAG_B  19072

// dynamic LDS layout (bytes), total 55936 (2 blocks/CU):
#define HHI_OFF  0        // ushort [8][16][72]            18432
#define WHH_OFF  18432    // 24 frags x 64 lanes x 16B     24576
#define WI_OFF   43008    // 12 frags x 64 lanes x 16B     12288
#define BHN_OFF  55296    // 64 f32                          256
#define WLC_OFF  55552    // 96 f32                          384
#define LDS_BYTES 55936

typedef __attribute__((ext_vector_type(8))) short bf16x8;
typedef __attribute__((ext_vector_type(4))) float f32x4;
typedef __attribute__((ext_vector_type(2))) float f32x2;

__device__ __forceinline__ ushort bf16rn(float f) {
    uint x = __float_as_uint(f);
    return (ushort)((x + 0x7fffu + ((x >> 16) & 1u)) >> 16);
}
__device__ __forceinline__ uint cvtpk_bf16(float lo, float hi) {
    uint r;
    asm("v_cvt_pk_bf16_f32 %0, %1, %2" : "=v"(r) : "v"(lo), "v"(hi));
    return r;
}
__device__ __forceinline__ float exp2p_(float x) {   // 2^x
    float r; asm("v_exp_f32 %0, %1" : "=v"(r) : "v"(x)); return r;
}
__device__ __forceinline__ float exp2n_(float x) {   // 2^-x (free neg modifier)
    float r; asm("v_exp_f32 %0, -%1" : "=v"(r) : "v"(x)); return r;
}
__device__ __forceinline__ float sigm(float v) {
    return __builtin_amdgcn_rcpf(1.0f + __expf(-v));
}

// ---------------- pre-kernel: build scaled gic + bf16 fragment tables in ws ----------------
extern "C" __global__ void __launch_bounds__(256)
traj_gru_pre(const float* __restrict__ Wloc, const float* __restrict__ bloc,
             const float* __restrict__ tt, const float* __restrict__ Wih,
             const float* __restrict__ Whh, const float* __restrict__ bih,
             const float* __restrict__ bhh, float* __restrict__ ws)
{
    const int b = blockIdx.x, tid = threadIdx.x;
    if (b < 36) {
        if (tid < 64) {
            const int er = tid & 15, cp = tid >> 4;
            const float* src;
            float s;
            if (b < 8) {            // wih R (0-3), Z (4-7): scale log2e
                int g = b >> 2, a = b & 3;
                src = Wih + (size_t)(g * 64 + a * 16 + er) * 64 + 8 * cp;
                s = LOG2E;
            } else if (b < 32) {    // whh frags: r,z -> log2e; n -> 2log2e
                int t = b - 8, g = t >> 3, r = t & 7, a = r >> 1, f = r & 1;
                src = Whh + (size_t)(g * 64 + a * 16 + er) * 64 + 32 * f + 8 * cp;
                s = (g == 2) ? 2.0f * LOG2E : LOG2E;
            } else {                // wih n-gate: 2log2e
                int a = b - 32;
                src = Wih + (size_t)(128 + a * 16 + er) * 64 + 8 * cp;
                s = 2.0f * LOG2E;
            }
            union { ushort u[8]; bf16x8 v; } fr;
            #pragma unroll
            for (int j = 0; j < 8; ++j) fr.u[j] = bf16rn(s * src[j]);
            *(bf16x8*)((char*)ws + WS_FRAG_B + ((size_t)b * 64 + tid) * 16) = fr.v;
        }
    } else if (b < 38) {
        const int base = (b - 36) * 2304;
        for (int i = tid; i < 2304; i += 256) {
            int idx = base + i, t = idx / 192, g = idx % 192;
            float acc = bih[g] + (g < 128 ? bhh[g] : 0.0f);
            const float* ttr = tt + t * 32;
            const float* wr  = Wih + g * 64 + 32;
            #pragma unroll
            for (int k = 0; k < 32; ++k) {
                float e = ttr[k];
                e = fmaxf(e, 0.2f * e);
                acc = fmaf(wr[k], e, acc);
            }
            ws[WS_GIC_F + idx] = acc * (g < 128 ? LOG2E : 2.0f * LOG2E);
        }
    } else {
        if (tid < 64) ws[WS_BHN_F + tid] = 2.0f * LOG2E * bhh[128 + tid];
        if (tid < 96) ws[WS_WLC_F + tid] = (tid < 64) ? Wloc[tid] : bloc[tid - 64];
    }
}

// ---------------- main kernel (R7 structure; n-gate hi-only; 4 waves/SIMD) ----------------
extern "C" __global__ void __launch_bounds__(512, 4)
traj_gru_mfma(const float* __restrict__ x, const float* __restrict__ ws,
              const float* __restrict__ Wpred, const float* __restrict__ bpred,
              float* __restrict__ out)
{
    extern __shared__ __align__(16) char L[];
    float*  Lf   = (float*)L;
    char*   whhS = L + WHH_OFF;
    char*   wiS  = L + WI_OFF;

    const int tid  = threadIdx.x;
    const int lane = tid & 63;
    const int wid  = tid >> 6;       // wave 0..7
    const int er   = lane & 15;      // A-row / B-col / D-col index
    const int cp   = lane >> 4;      // k-block / D-row-block

    // ---- stage all 36 weight frags ws -> LDS (coalesced 16B chunks) ----
    const char* fb = (const char*)ws + WS_FRAG_B;
    for (int i = tid; i < 36 * 64; i += 512) {
        int f = i >> 6, l = i & 63;
        bf16x8 v = *(const bf16x8*)(fb + (size_t)i * 16);
        char* dst;
        if (f < 8)       dst = wiS  + ((size_t)f * 64 + l) * 16;        // R,Z input frags
        else if (f < 32) dst = whhS + ((size_t)(f - 8) * 64 + l) * 16;  // recurrent frags
        else             dst = wiS  + ((size_t)(f - 24) * 64 + l) * 16; // n input frags -> 8..11
        *(bf16x8*)dst = v;
    }
    if (tid < 64) Lf[BHN_OFF / 4 + tid] = ws[WS_BHN_F + tid];
    if (tid < 96) Lf[WLC_OFF / 4 + tid] = ws[WS_WLC_F + tid];
    __syncthreads();   // the only barrier

    const f32x2* wlc2 = (const f32x2*)(Lf + WLC_OFF / 4);
    ushort* Hhi = (ushort*)(L + HHI_OFF) + (size_t)(wid * 16) * 72;

    // ---- main loop: wave owns 16 elements ----
    const long long eg = (long long)(blockIdx.x * 8 + wid) * 16 + er;
    const float* xr = x + eg * (TN * 2);

    f32x2 hold2[4][2];
    #pragma unroll
    for (int a = 0; a < 4; ++a)
        #pragma unroll
        for (int p = 0; p < 2; ++p) hold2[a][p] = (f32x2){0.0f, 0.0f};

    const f32x2 one2    = {1.0f, 1.0f};
    const f32x2 negtwo2 = {-2.0f, -2.0f};

    float2 xv = *(const float2*)(xr);   // t=0 prefetched

    #pragma unroll 1
    for (int t = 0; t < TN; ++t) {
        const int tn = (t + 1 < TN) ? t + 1 : TN - 1;
        float2 xv_next = *(const float2*)(xr + tn * 2);

        // ex B-frag: ex[k = 8cp+j][elem = er]
        union { uint u[4]; bf16x8 v; } exf;
        {
            f32x2 xx = {xv.x, xv.x}, yy = {xv.y, xv.y};
            #pragma unroll
            for (int jp = 0; jp < 4; ++jp) {
                int kp = 4 * cp + jp;
                f32x2 w1 = wlc2[kp], w2 = wlc2[16 + kp], bl = wlc2[32 + kp];
                f32x2 v = __builtin_elementwise_fma(xx, w1,
                          __builtin_elementwise_fma(yy, w2, bl));
                float v0 = fmaxf(v.x, 0.2f * v.x);
                float v1 = fmaxf(v.y, 0.2f * v.y);
                exf.u[jp] = cvtpk_bf16(v0, v1);
            }
        }

        // accumulator init: gic from global (L1/L2-resident), bhn from LDS
        const float* gt = ws + WS_GIC_F + t * 192;
        f32x4 accR[4], accZ[4], accNi[4], accNh[4];
        #pragma unroll
        for (int a = 0; a < 4; ++a) {
            accR[a]  = *(const f32x4*)(gt + a * 16 + 4 * cp);
            accZ[a]  = *(const f32x4*)(gt + 64 + a * 16 + 4 * cp);
            accNi[a] = *(const f32x4*)(gt + 128 + a * 16 + 4 * cp);
            accNh[a] = *(const f32x4*)(Lf + BHN_OFF / 4 + a * 16 + 4 * cp);
        }

        // input-part MFMAs (K=32), weights from LDS
        #pragma unroll
        for (int a = 0; a < 4; ++a) {
            bf16x8 wr = *(const bf16x8*)(wiS + ((size_t)a * 64 + lane) * 16);
            bf16x8 wz = *(const bf16x8*)(wiS + ((size_t)(4 + a) * 64 + lane) * 16);
            bf16x8 wn = *(const bf16x8*)(wiS + ((size_t)(8 + a) * 64 + lane) * 16);
            accR[a]  = __builtin_amdgcn_mfma_f32_16x16x32_bf16(wr, exf.v, accR[a], 0, 0, 0);
            accZ[a]  = __builtin_amdgcn_mfma_f32_16x16x32_bf16(wz, exf.v, accZ[a], 0, 0, 0);
            accNi[a] = __builtin_amdgcn_mfma_f32_16x16x32_bf16(wn, exf.v, accNi[a], 0, 0, 0);
        }

        // recurrent MFMAs (K=64, h = bf16 hi only; f32 master state stays in hold2)
        if (t > 0) {
            bf16x8 hhi0 = *(const bf16x8*)&Hhi[er * 72 + 8 * cp];
            bf16x8 hhi1 = *(const bf16x8*)&Hhi[er * 72 + 32 + 8 * cp];
            #pragma unroll
            for (int a = 0; a < 4; ++a) {
                bf16x8 wr0 = *(const bf16x8*)(whhS + ((size_t)(a * 2 + 0) * 64 + lane) * 16);
                bf16x8 wr1 = *(const bf16x8*)(whhS + ((size_t)(a * 2 + 1) * 64 + lane) * 16);
                accR[a] = __builtin_amdgcn_mfma_f32_16x16x32_bf16(wr0, hhi0, accR[a], 0, 0, 0);
                accR[a] = __builtin_amdgcn_mfma_f32_16x16x32_bf16(wr1, hhi1, accR[a], 0, 0, 0);
                bf16x8 wz0 = *(const bf16x8*)(whhS + ((size_t)(8 + a * 2 + 0) * 64 + lane) * 16);
                bf16x8 wz1 = *(const bf16x8*)(whhS + ((size_t)(8 + a * 2 + 1) * 64 + lane) * 16);
                accZ[a] = __builtin_amdgcn_mfma_f32_16x16x32_bf16(wz0, hhi0, accZ[a], 0, 0, 0);
                accZ[a] = __builtin_amdgcn_mfma_f32_16x16x32_bf16(wz1, hhi1, accZ[a], 0, 0, 0);
                bf16x8 wn0 = *(const bf16x8*)(whhS + ((size_t)(16 + a * 2 + 0) * 64 + lane) * 16);
                bf16x8 wn1 = *(const bf16x8*)(whhS + ((size_t)(16 + a * 2 + 1) * 64 + lane) * 16);
                accNh[a] = __builtin_amdgcn_mfma_f32_16x16x32_bf16(wn0, hhi0, accNh[a], 0, 0, 0);
                accNh[a] = __builtin_amdgcn_mfma_f32_16x16x32_bf16(wn1, hhi1, accNh[a], 0, 0, 0);
            }
        }

        // epilogue: packed-f32 gate math; acc pre-scaled by log2e (r,z) / 2log2e (n)
        #pragma unroll
        for (int a = 0; a < 4; ++a) {
            uint hiw[2];
            #pragma unroll
            for (int p = 0; p < 2; ++p) {
                f32x2 aR  = {accR[a][2 * p],  accR[a][2 * p + 1]};
                f32x2 aZ  = {accZ[a][2 * p],  accZ[a][2 * p + 1]};
                f32x2 aNi = {accNi[a][2 * p], accNi[a][2 * p + 1]};
                f32x2 aNh = {accNh[a][2 * p], accNh[a][2 * p + 1]};
                f32x2 eR = {exp2n_(aR.x), exp2n_(aR.y)};
                f32x2 eZ = {exp2n_(aZ.x), exp2n_(aZ.y)};
                f32x2 dR = eR + one2;
                f32x2 dZ = eZ + one2;
                f32x2 r  = {__builtin_amdgcn_rcpf(dR.x), __builtin_amdgcn_rcpf(dR.y)};
                f32x2 z  = {__builtin_amdgcn_rcpf(dZ.x), __builtin_amdgcn_rcpf(dZ.y)};
                f32x2 np = __builtin_elementwise_fma(r, aNh, aNi);     // 2log2e * npre
                f32x2 e2 = {exp2p_(np.x), exp2p_(np.y)};
                f32x2 d2 = e2 + one2;
                f32x2 rc = {__builtin_amdgcn_rcpf(d2.x), __builtin_amdgcn_rcpf(d2.y)};
                f32x2 n  = __builtin_elementwise_fma(rc, negtwo2, one2);  // tanh
                f32x2 hm = hold2[a][p] - n;
                f32x2 h  = __builtin_elementwise_fma(z, hm, n);
                hold2[a][p] = h;
                hiw[p] = cvtpk_bf16(h.x, h.y);
            }
            uint2 whiv = {hiw[0], hiw[1]};
            *(uint2*)&Hhi[er * 72 + 16 * a + 4 * cp] = whiv;
        }

        xv = xv_next;
    }

    // ---- prediction head ----
    float part = 0.0f;
    #pragma unroll
    for (int a = 0; a < 4; ++a) {
        f32x4 wp = *(const f32x4*)(Wpred + 16 * a + 4 * cp);
        #pragma unroll
        for (int p = 0; p < 2; ++p) {
            part = fmaf(hold2[a][p].x, wp[2 * p], part);
            part = fmaf(hold2[a][p].y, wp[2 * p + 1], part);
        }
    }
    part += __shfl_xor(part, 16);
    part += __shfl_xor(part, 32);
    if (cp == 0) out[eg] = sigm(part + bpred[0]);
}

extern "C" void kernel_launch(void* const* d_in, const int* in_sizes, int n_in,
                              void* d_out, int out_size, void* d_ws, size_t ws_size,
                              hipStream_t stream) {
    const float* x     = (const float*)d_in[0];
    const float* Wloc  = (const float*)d_in[1];
    const float* bloc  = (const float*)d_in[2];
    const float* tt    = (const float*)d_in[3];
    const float* Wih   = (const float*)d_in[4];
    const float* Whh   = (const float*)d_in[5];
    const float* bih   = (const float*)d_in[6];
    const float* bhh   = (const float*)d_in[7];
    const float* Wpred = (const float*)d_in[8];
    const float* bpred = (const float*)d_in[9];
    float* out = (float*)d_out;
    float* ws  = (float*)d_ws;

    (void)hipFuncSetAttribute((const void*)traj_gru_mfma,
                              hipFuncAttributeMaxDynamicSharedMemorySize, LDS_BYTES);

    hipLaunchKernelGGL(traj_gru_pre, dim3(39), dim3(256), 0, stream,
                       Wloc, bloc, tt, Wih, Whh, bih, bhh, ws);
    // 65536 elements / (8 waves * 16 elem) = 512 blocks of 512 threads = 2 blocks/CU
    hipLaunchKernelGGL(traj_gru_mfma, dim3(512), dim3(512), LDS_BYTES, stream,
                       x, ws, Wpred, bpred, out);
}